// Round 1
// baseline (70.054 us; speedup 1.0000x reference)
//
#include <hip/hip_runtime.h>
#include <math.h>

#define EPSF 1e-6f
#define N_PTS 1024
#define BT 32
#define QB 256      // queries per block
#define RCHUNK 256  // refs per wave (4 waves cover all 1024)

// ---------------------------------------------------------------------------
// Fully fused chamfer: grid (4 query-chunks, 32 batches, 2 directions) =
// 256 blocks = 1 block/CU; 256 threads = 4 waves = 1 wave/SIMD.
// All 1024 refs staged once in LDS as float4(-2rx,-2ry,-2rz,|r|^2) (16 KB).
// Wave w scans ref chunk [256w, 256w+256) for the block's 256 queries,
// Q=4 queries/lane. Refs processed in PAIRS:
//   v0 = 3-FMA chain(ref i), v1 = 3-FMA chain(ref i+1),
//   m  = fminf(m, fminf(v0,v1))  -> v_min3_f32
// = 7 VALU per 2 pairs, 28 VALU per broadcast ds_read_b128 (LDS pipe idle).
// Per-lane VALU = 3584 inst ~= 7.2K cyc = the machine-wide VALU floor.
// Cross-wave min via pmin[4][256] in LDS (q2 folded in: min and the 0-clamp
// both commute with the per-query constant), then sqrt + wave-sum +
// one atomicAdd per block. No workspace, no second kernel.
// ---------------------------------------------------------------------------
__global__ __launch_bounds__(256) void chamfer_fused(
    const float* __restrict__ x, const float* __restrict__ y,
    float* __restrict__ out) {
  const int t   = threadIdx.x;
  const int w   = t >> 6;        // wave 0..3
  const int l   = t & 63;        // lane
  const int qc  = blockIdx.x;    // 0..3
  const int b   = blockIdx.y;    // 0..31
  const int dir = blockIdx.z;    // 0: query=x ref=y ; 1: swapped

  const float* qarr = dir ? y : x;
  const float* rarr = dir ? x : y;
  const float* qb = qarr + (size_t)b * (N_PTS * 3) + (size_t)qc * (QB * 3);
  const float* rb = rarr + (size_t)b * (N_PTS * 3);

  __shared__ float4 s[N_PTS];        // 16 KB
  __shared__ float pmin[4][QB];      // 4 KB
  __shared__ float wsum[4];

  // Stage all 1024 refs (4 per thread, coalesced 12 B/lane reads).
#pragma unroll
  for (int r = 0; r < 4; ++r) {
    const int i = t + 256 * r;
    const float rx = rb[i * 3 + 0];
    const float ry = rb[i * 3 + 1];
    const float rz = rb[i * 3 + 2];
    s[i] = make_float4(-2.0f * rx, -2.0f * ry, -2.0f * rz,
                       rx * rx + ry * ry + rz * rz);
  }

  // Load this lane's 4 queries (coalesced 12 B/lane) while staging lands.
  float qx[4], qy[4], qz[4], q2[4], m[4];
#pragma unroll
  for (int k = 0; k < 4; ++k) {
    const int j = l + 64 * k;
    qx[k] = qb[j * 3 + 0];
    qy[k] = qb[j * 3 + 1];
    qz[k] = qb[j * 3 + 2];
    q2[k] = qx[k] * qx[k] + qy[k] * qy[k] + qz[k] * qz[k];
    m[k] = 3.4e38f;
  }
  __syncthreads();

  // Wave-private 256-ref chunk; broadcast ds_read_b128 serves all lanes.
  const float4* sc = s + w * RCHUNK;
#pragma unroll 4
  for (int i = 0; i < RCHUNK; i += 2) {
    const float4 r0 = sc[i];
    const float4 r1 = sc[i + 1];
#pragma unroll
    for (int k = 0; k < 4; ++k) {
      float v0 = fmaf(qx[k], r0.x, r0.w);
      v0 = fmaf(qy[k], r0.y, v0);
      v0 = fmaf(qz[k], r0.z, v0);
      float v1 = fmaf(qx[k], r1.x, r1.w);
      v1 = fmaf(qy[k], r1.y, v1);
      v1 = fmaf(qz[k], r1.z, v1);
      m[k] = fminf(m[k], fminf(v0, v1));  // -> v_min3_f32
    }
  }

  // Publish partial (q2 + min over this wave's chunk); conflict-free writes.
#pragma unroll
  for (int k = 0; k < 4; ++k) pmin[w][l + 64 * k] = q2[k] + m[k];
  __syncthreads();

  // Thread t finishes query t: min over 4 wave-partials, clamp, sqrt.
  const float v = fminf(fminf(pmin[0][t], pmin[1][t]),
                        fminf(pmin[2][t], pmin[3][t]));
  float d = sqrtf(EPSF + fmaxf(v, 0.0f));

  for (int off = 32; off > 0; off >>= 1) d += __shfl_down(d, off, 64);
  if (l == 0) wsum[w] = d;
  __syncthreads();
  if (t == 0) {
    atomicAdd(out, (wsum[0] + wsum[1] + wsum[2] + wsum[3]) *
                       (1.0f / 32768.0f));
  }
}

extern "C" void kernel_launch(void* const* d_in, const int* in_sizes, int n_in,
                              void* d_out, int out_size, void* d_ws, size_t ws_size,
                              hipStream_t stream) {
  const float* x = (const float*)d_in[0];
  const float* y = (const float*)d_in[1];
  float* out = (float*)d_out;

  // d_out is re-poisoned to 0xAA before every timed replay; zero it first.
  hipMemsetAsync(out, 0, sizeof(float) * out_size, stream);

  chamfer_fused<<<dim3(4, BT, 2), 256, 0, stream>>>(x, y, out);
}

// Round 2
// 66.202 us; speedup vs baseline: 1.0582x; 1.0582x over previous
//
#include <hip/hip_runtime.h>
#include <math.h>

#define EPSF 1e-6f
#define N_PTS 1024
#define BT 32
#define QB 128                 // queries per block
#define NW 8                   // waves per block
#define RCHUNK (N_PTS / NW)    // 128 refs per wave

// ---------------------------------------------------------------------------
// Fused chamfer, occupancy-fixed: grid (8 query-chunks, 32 batches, 2 dirs)
// = 512 blocks x 512 threads (8 waves) -> 2 blocks/CU, 16 waves/CU,
// 4 waves/SIMD (round-1's 1 wave/SIMD exposed every latency; this hides it).
// All 1024 refs staged once per block in LDS as float4(-2r, |r|^2) (16 KB).
// Wave w scans ref chunk [128w, 128w+128) for the block's 128 queries,
// Q=2 queries/lane. Refs in PAIRS: 6 FMA + v_min3_f32 per query-pair
// = 14 VALU per 2 broadcast ds_read_b128 (uniform address -> conflict-free).
// Per-lane critical path: 64 iters x 14 VALU ~= 1.8K cyc (~0.75 us).
// Cross-wave min via pmin[8][128] (q2 folded in; min/clamp commute), then
// sqrt + wave-shuffle sum + one atomicAdd per block. No workspace.
// ---------------------------------------------------------------------------
__global__ __launch_bounds__(512) void chamfer_fused(
    const float* __restrict__ x, const float* __restrict__ y,
    float* __restrict__ out) {
  const int t   = threadIdx.x;
  const int w   = t >> 6;        // wave 0..7
  const int l   = t & 63;        // lane
  const int qc  = blockIdx.x;    // 0..7
  const int b   = blockIdx.y;    // 0..31
  const int dir = blockIdx.z;    // 0: query=x ref=y ; 1: swapped

  const float* qarr = dir ? y : x;
  const float* rarr = dir ? x : y;
  const float* qb = qarr + (size_t)b * (N_PTS * 3) + (size_t)qc * (QB * 3);
  const float* rb = rarr + (size_t)b * (N_PTS * 3);

  __shared__ float4 s[N_PTS];        // 16 KB
  __shared__ float pmin[NW][QB];     // 4 KB
  __shared__ float wsum[NW];

  // Stage all 1024 refs (2 per thread, coalesced 12 B/lane reads).
#pragma unroll
  for (int r = 0; r < 2; ++r) {
    const int i = t + 512 * r;
    const float rx = rb[i * 3 + 0];
    const float ry = rb[i * 3 + 1];
    const float rz = rb[i * 3 + 2];
    s[i] = make_float4(-2.0f * rx, -2.0f * ry, -2.0f * rz,
                       rx * rx + ry * ry + rz * rz);
  }

  // Each lane owns queries {l, l+64}; identical across waves (L1-hot).
  float qx[2], qy[2], qz[2], q2[2], m[2];
#pragma unroll
  for (int k = 0; k < 2; ++k) {
    const int j = l + 64 * k;
    qx[k] = qb[j * 3 + 0];
    qy[k] = qb[j * 3 + 1];
    qz[k] = qb[j * 3 + 2];
    q2[k] = qx[k] * qx[k] + qy[k] * qy[k] + qz[k] * qz[k];
    m[k] = 3.4e38f;
  }
  __syncthreads();

  // Wave-private 128-ref chunk; broadcast ds_read_b128 serves all lanes.
  const float4* sc = s + w * RCHUNK;
#pragma unroll 4
  for (int i = 0; i < RCHUNK; i += 2) {
    const float4 r0 = sc[i];
    const float4 r1 = sc[i + 1];
#pragma unroll
    for (int k = 0; k < 2; ++k) {
      float v0 = fmaf(qx[k], r0.x, r0.w);
      v0 = fmaf(qy[k], r0.y, v0);
      v0 = fmaf(qz[k], r0.z, v0);
      float v1 = fmaf(qx[k], r1.x, r1.w);
      v1 = fmaf(qy[k], r1.y, v1);
      v1 = fmaf(qz[k], r1.z, v1);
      m[k] = fminf(m[k], fminf(v0, v1));  // -> v_min3_f32
    }
  }

  // Publish partial (q2 + min over this wave's chunk); conflict-free writes.
#pragma unroll
  for (int k = 0; k < 2; ++k) pmin[w][l + 64 * k] = q2[k] + m[k];
  __syncthreads();

  // Threads 0..127 finish one query each: min over 8 wave-partials.
  float d = 0.0f;
  if (t < QB) {
    float v = pmin[0][t];
#pragma unroll
    for (int ww = 1; ww < NW; ++ww) v = fminf(v, pmin[ww][t]);
    d = sqrtf(EPSF + fmaxf(v, 0.0f));
  }

  for (int off = 32; off > 0; off >>= 1) d += __shfl_down(d, off, 64);
  if (l == 0) wsum[w] = d;
  __syncthreads();
  if (t == 0) {
    float sb = 0.0f;
#pragma unroll
    for (int ww = 0; ww < NW; ++ww) sb += wsum[ww];
    atomicAdd(out, sb * (1.0f / 32768.0f));
  }
}

extern "C" void kernel_launch(void* const* d_in, const int* in_sizes, int n_in,
                              void* d_out, int out_size, void* d_ws, size_t ws_size,
                              hipStream_t stream) {
  const float* x = (const float*)d_in[0];
  const float* y = (const float*)d_in[1];
  float* out = (float*)d_out;

  // d_out is re-poisoned to 0xAA before every timed replay; zero it first.
  hipMemsetAsync(out, 0, sizeof(float) * out_size, stream);

  chamfer_fused<<<dim3(8, BT, 2), 512, 0, stream>>>(x, y, out);
}